// Round 5
// baseline (864.991 us; speedup 1.0000x reference)
//
#include <hip/hip_runtime.h>
#include <cstdint>

// ---------------- problem constants ----------------
static constexpr long long Bb = 16, Nn = 1024, FE = 512; // heads=2, g=512
static constexpr long long BN = Bb * Nn;        // 16384
static constexpr long long E1e = BN * FE;       // elems of [B,N,FE]
static constexpr long long E2n = BN * Nn;       // elems of [B,N,N]

// ---------------- workspace layout (bytes) ----------------
static constexpr long long O_WT  = 0;
static constexpr long long SZ_W512 = FE * FE * 2;          // 512x512 bf16
static constexpr long long O_WQT = O_WT + 6 * SZ_W512;
static constexpr long long SZ_W1K = Nn * Nn * 2;           // 1024x1024 bf16
static constexpr long long O_WKT = O_WQT + SZ_W1K;
static constexpr long long O_WVT = O_WKT + SZ_W1K;
static constexpr long long O_F1T = O_WVT + SZ_W1K;
static constexpr long long O_F2T = O_F1T + SZ_W1K;
static constexpr long long O_SLOTS = O_F2T + SZ_W1K;       // 13,631,488
static constexpr long long SLOT = E2n * 2;                 // 32 MiB
static constexpr long long O_S0 = O_SLOTS;                 // Cp -> Q -> o
static constexpr long long O_S1 = O_S0 + SLOT;             // Cq45 -> K -> x
static constexpr long long O_S2 = O_S1 + SLOT;             // Cq6 -> Vt -> h
static constexpr long long O_E0 = O_S2 + SLOT;             // ass -> scores h0
static constexpr long long O_E1 = O_E0 + SLOT;             // (FmsB|FsB) -> asq -> scores h1
static constexpr long long O_E2 = O_E1 + SLOT;             // (FqB|C2) -> aqq
static constexpr long long WS_NEED = O_E2 + SLOT;          // ~205 MiB
// temporaries parked inside E1/E2 before those are written:
static constexpr long long O_FMSB = O_E1;                  // dead after Cp
static constexpr long long O_FSB  = O_E1 + E1e * 2;        // dead after C2 (asq overwrites)
static constexpr long long O_FQB  = O_E2;                  // dead after Cq45/Cq6
static constexpr long long O_C2   = O_E2 + E1e * 2;        // dead after asq (aqq overwrites)

// ---------------- helpers ----------------
typedef __attribute__((ext_vector_type(8))) short short8;
typedef __attribute__((ext_vector_type(4))) float f32x4;

static __device__ __forceinline__ unsigned short f2bf(float f) {
  union { float f; unsigned u; } x; x.f = f;
  unsigned r = x.u + 0x7FFFu + ((x.u >> 16) & 1u);
  return (unsigned short)(r >> 16);
}
static __device__ __forceinline__ float bf2f(unsigned short h) {
  union { unsigned u; float f; } x; x.u = ((unsigned)h) << 16; return x.f;
}
static __device__ __forceinline__ void gload16(const void* g, void* l) {
  __builtin_amdgcn_global_load_lds(
      (const __attribute__((address_space(1))) unsigned int*)g,
      (__attribute__((address_space(3))) unsigned int*)l, 16, 0, 0);
}

// ---------------- bf16 NT GEMM, 256x256 tile, B direct-to-register ----------
// C[m,n] = sum_k A[m,k]*B[n,k].  8 waves (2M x 4N), per-wave output 128x64.
// BK=32 per K-step.  A: LDS ring-4 (4 x 16 KiB, 64 KiB total), staged via
// global_load_lds 3 tiles ahead.  B: NO LDS — each wave loads its 4 B-frags
// straight global->VGPR (lane(lrow,quad) reads B[f*16+lrow][k0+quad*8..+8] =
// coalesced dwordx4), double-buffered be/bo one step ahead.  This cuts LDS
// read traffic 96->64 KiB/step (below the ~310cyc MFMA pipe time) and removes
// B from the post-barrier read burst, so the A-read cascade (m-outer MFMA
// order, first MFMA needs only af[0]) hides under MFMA.
// Per step: {READ_A(t) 8 ds_read; STAGE_A(t+3) 2 gload_lds; LOADB(t+1) 4 vmem;
//            MFMA(t) 32; vmcnt(6); barrier}.
// vmcnt(6) leaves exactly {st(t+3):2, B(t+1):4} in flight (ledger verified);
// compiler inserts the data-dependence wait for B(t) before MFMA itself.
// A LDS swizzle (verified 0 conflicts): slot s of row r holds k-slot
// s ^ ((r>>1)&3); linear gload_lds dest + pre-swizzled global source.
// Batch z decodes z1=z&15, z2=z>>4: operand offset = z1*s? + z2*h?.
// EP: 1 = bf16 out, 2 = bf16 relu out, 3 = f32 out + bf16 residual R.
template <int EP>
__global__ __launch_bounds__(512, 2) void gemm256(
    const unsigned short* __restrict__ A, long long sA, long long hA, int lda,
    const unsigned short* __restrict__ B, long long sB, long long hB, int ldb,
    void* __restrict__ Cv, long long sC, long long hC, int ldc,
    const void* __restrict__ Rv, long long sR, int K) {
  extern __shared__ unsigned short lds[];
  const int tid = threadIdx.x;
  const int lane = tid & 63;
  const int wave = tid >> 6;
  const int wm = wave >> 2, wn = wave & 3;
  const int lrow = lane & 15, quad = lane >> 4;

  // bijective XCD swizzle on the flat workgroup id (launcher: nwg % 8 == 0)
  const int gx = gridDim.x;
  const int nxy = gx * gridDim.y;
  const int nwg = nxy * gridDim.z;
  int wg = blockIdx.x + gx * blockIdx.y + nxy * blockIdx.z;
  wg = (wg & 7) * (nwg >> 3) + (wg >> 3);
  const int bz = wg / nxy;
  const int rem = wg - bz * nxy;
  const int by = rem / gx;
  const int bx = rem - by * gx;
  const int z1 = bz & 15, z2 = bz >> 4;

  const long long bm = (long long)bx * 256;
  const long long bn = (long long)by * 256;
  const unsigned short* Ab = A + z1 * sA + z2 * hA + bm * lda;
  const unsigned short* Bp = B + z1 * sB + z2 * hB + bn * ldb;

  // A staging: thread covers row (tid>>2) (+128 2nd round), 16B slot (tid&3).
  // source k-slot pre-swizzled so LINEAR LDS image == swizzled layout.
  const int srow = tid >> 2;
  const int scol = ((tid & 3) ^ ((tid >> 3) & 3)) * 8;  // elems
  unsigned short* ldst = lds + tid * 8;
  auto STAGE = [&](int tt) {
    unsigned short* d = ldst + (tt & 3) * 8192;
    const long long ko = (long long)tt * 32 + scol;
    gload16(Ab + (long long)srow * lda + ko, d);
    gload16(Ab + (long long)(srow + 128) * lda + ko, d + 4096);
  };

  // A read side: lane (lrow,quad) reads swizzled slot quad ^ ((lrow>>1)&3).
  const int swq = (quad ^ ((lrow >> 1) & 3)) * 8;
  const int a_off = (wm * 128 + lrow) * 32 + swq;

  // B fragment pointers (per-lane, direct global; no swizzle needed)
  const unsigned short* Bf[4];
#pragma unroll
  for (int f = 0; f < 4; ++f)
    Bf[f] = Bp + (long long)(wn * 64 + f * 16 + lrow) * ldb + quad * 8;

  f32x4 acc[8][4];
#pragma unroll
  for (int m = 0; m < 8; ++m)
#pragma unroll
    for (int n = 0; n < 4; ++n) acc[m][n] = (f32x4){0.f, 0.f, 0.f, 0.f};

  short8 af[8], be[4], bo[4];
  auto READ_A = [&](int tt) {
    const unsigned short* lb = lds + (tt & 3) * 8192;
#pragma unroll
    for (int m = 0; m < 8; ++m) af[m] = *(const short8*)&lb[a_off + m * 512];
  };
  auto LOADB = [&](int tt, short8* dst) {
#pragma unroll
    for (int f = 0; f < 4; ++f)
      dst[f] = *(const short8*)(Bf[f] + (long long)tt * 32);
  };
  auto MFMAC = [&](const short8* bb) {
    __builtin_amdgcn_s_setprio(1);
#pragma unroll
    for (int m = 0; m < 8; ++m)
#pragma unroll
      for (int n = 0; n < 4; ++n)
        acc[m][n] = __builtin_amdgcn_mfma_f32_16x16x32_bf16(af[m], bb[n], acc[m][n], 0, 0, 0);
    __builtin_amdgcn_s_setprio(0);
  };

  const int nt = K >> 5;   // 16 or 32 here (even, >= 16)
  // prologue: stage tiles 0-2 (6 gloads), load B(0) -> be
  STAGE(0); STAGE(1); STAGE(2);
  LOADB(0, be);
  asm volatile("s_waitcnt vmcnt(8)" ::: "memory");   // retire st(0)
  __builtin_amdgcn_s_barrier();                      // buf0 globally ready
  int t = 0;
  for (; t < nt - 6; t += 2) {
    // even step t (uses be, buf[t])
    READ_A(t);
    STAGE(t + 3);
    LOADB(t + 1, bo);
    MFMAC(be);
    asm volatile("s_waitcnt vmcnt(6)" ::: "memory"); // leaves st(t+3), B(t+1)
    __builtin_amdgcn_s_barrier();
    // odd step t+1 (uses bo, buf[t+1])
    READ_A(t + 1);
    STAGE(t + 4);
    LOADB(t + 2, be);
    MFMAC(bo);
    asm volatile("s_waitcnt vmcnt(6)" ::: "memory");
    __builtin_amdgcn_s_barrier();
  }
  // ---- tail: 6 steps nt-6 .. nt-1 ----
  // t = nt-6 (even)
  READ_A(nt - 6); STAGE(nt - 3); LOADB(nt - 5, bo); MFMAC(be);
  asm volatile("s_waitcnt vmcnt(6)" ::: "memory");
  __builtin_amdgcn_s_barrier();
  // t = nt-5 (odd)
  READ_A(nt - 5); STAGE(nt - 2); LOADB(nt - 4, be); MFMAC(bo);
  asm volatile("s_waitcnt vmcnt(6)" ::: "memory");
  __builtin_amdgcn_s_barrier();
  // t = nt-4 (even)
  READ_A(nt - 4); STAGE(nt - 1); LOADB(nt - 3, bo); MFMAC(be);
  asm volatile("s_waitcnt vmcnt(6)" ::: "memory");
  __builtin_amdgcn_s_barrier();
  // t = nt-3 (odd)
  READ_A(nt - 3); LOADB(nt - 2, be); MFMAC(bo);
  asm volatile("s_waitcnt vmcnt(4)" ::: "memory");
  __builtin_amdgcn_s_barrier();
  // t = nt-2 (even)
  READ_A(nt - 2); LOADB(nt - 1, bo); MFMAC(be);
  asm volatile("s_waitcnt vmcnt(4)" ::: "memory");
  __builtin_amdgcn_s_barrier();
  // t = nt-1 (odd)
  READ_A(nt - 1); MFMAC(bo);

  // epilogue: C/D map col=lane&15, row=quad*4+r (verified m89/m91)
  const long long cm = bm + wm * 128, cn = bn + wn * 64;
  const long long cz = z1 * sC + z2 * hC;
#pragma unroll
  for (int mt = 0; mt < 8; ++mt) {
#pragma unroll
    for (int ntl = 0; ntl < 4; ++ntl) {
      long long col = cn + ntl * 16 + lrow;
      long long row0 = cm + mt * 16 + quad * 4;
#pragma unroll
      for (int r = 0; r < 4; ++r) {
        long long row = row0 + r;
        float v = acc[mt][ntl][r];
        long long idx = cz + row * ldc + col;
        if (EP == 1) ((unsigned short*)Cv)[idx] = f2bf(v);
        else if (EP == 2) ((unsigned short*)Cv)[idx] = f2bf(v > 0.f ? v : 0.f);
        else {
          float rr = bf2f(((const unsigned short*)Rv)[z1 * sR + row * ldc + col]);
          ((float*)Cv)[idx] = v + rr;
        }
      }
    }
  }
}

// ---------------- merged cast f32 -> bf16 for Fs, Fq, Fms ----------------
__global__ __launch_bounds__(256) void cast3_k(const float* __restrict__ i0,
                                               const float* __restrict__ i1,
                                               const float* __restrict__ i2,
                                               unsigned short* o0, unsigned short* o1,
                                               unsigned short* o2) {
  const float* in = (blockIdx.y == 0) ? i0 : (blockIdx.y == 1) ? i1 : i2;
  unsigned short* out = (blockIdx.y == 0) ? o0 : (blockIdx.y == 1) ? o1 : o2;
  long long i = (long long)blockIdx.x * 256 + threadIdx.x;
  float4 v = ((const float4*)in)[i];
  ushort4 o; o.x = f2bf(v.x); o.y = f2bf(v.y); o.z = f2bf(v.z); o.w = f2bf(v.w);
  ((ushort4*)out)[i] = o;
}

// ---------------- merged transpose+cast: z selects source ----------------
__global__ __launch_bounds__(256) void tcast6_k(const float* p0, const float* p1,
                                                const float* p2, const float* p3,
                                                const float* p4, const float* p5,
                                                unsigned short* outb, int rows, int cols) {
  const float* src[6] = {p0, p1, p2, p3, p4, p5};
  const float* in = src[blockIdx.z];
  unsigned short* out = outb + (long long)blockIdx.z * rows * cols;
  __shared__ float t[32][33];
  const int c0 = blockIdx.x * 32, r0 = blockIdx.y * 32;
  const int tx = threadIdx.x, ty = threadIdx.y; // block (32,8)
#pragma unroll
  for (int i = 0; i < 4; ++i) {
    int r = r0 + ty + i * 8;
    t[ty + i * 8][tx] = in[(long long)r * cols + c0 + tx];
  }
  __syncthreads();
#pragma unroll
  for (int i = 0; i < 4; ++i) {
    int c = c0 + ty + i * 8;
    out[(long long)c * rows + r0 + tx] = f2bf(t[tx][ty + i * 8]);
  }
}

// ---------------- in-place row softmax over bf16 (1024 cols), scaled ----------------
__global__ __launch_bounds__(256) void softmax_bf(unsigned short* __restrict__ S, float scale) {
  __shared__ float redA[4], redB[4];
  const long long row = blockIdx.x;
  const int t = threadIdx.x, wave = t >> 6, lane = t & 63;
  ushort4 u = ((ushort4*)(S + row * 1024))[t];
  float v0 = bf2f(u.x) * scale, v1 = bf2f(u.y) * scale, v2 = bf2f(u.z) * scale, v3 = bf2f(u.w) * scale;
  float m = fmaxf(fmaxf(v0, v1), fmaxf(v2, v3));
#pragma unroll
  for (int o = 32; o; o >>= 1) m = fmaxf(m, __shfl_down(m, o));
  if (lane == 0) redA[wave] = m;
  __syncthreads();
  m = fmaxf(fmaxf(redA[0], redA[1]), fmaxf(redA[2], redA[3]));
  float e0 = __expf(v0 - m), e1 = __expf(v1 - m), e2 = __expf(v2 - m), e3 = __expf(v3 - m);
  float s = e0 + e1 + e2 + e3;
#pragma unroll
  for (int o = 32; o; o >>= 1) s += __shfl_down(s, o);
  if (lane == 0) redB[wave] = s;
  __syncthreads();
  s = redB[0] + redB[1] + redB[2] + redB[3];
  float inv = 1.f / s;
  ushort4 ob; ob.x = f2bf(e0 * inv); ob.y = f2bf(e1 * inv); ob.z = f2bf(e2 * inv); ob.w = f2bf(e3 * inv);
  ((ushort4*)(S + row * 1024))[t] = ob;
}

// ---------------- LN1: x = LN(o + aqq)*g + b -> bf16 ----------------
__global__ __launch_bounds__(256) void ln1_k(const unsigned short* __restrict__ O,
                                             const unsigned short* __restrict__ Aq,
                                             const float* __restrict__ g, const float* __restrict__ b,
                                             unsigned short* __restrict__ xb) {
  __shared__ float redA[4], redB[4];
  const long long row = blockIdx.x;
  const int t = threadIdx.x, wave = t >> 6, lane = t & 63;
  ushort4 ou = ((const ushort4*)(O + row * 1024))[t];
  ushort4 au = ((const ushort4*)(Aq + row * 1024))[t];
  float v0 = bf2f(ou.x) + bf2f(au.x), v1 = bf2f(ou.y) + bf2f(au.y);
  float v2 = bf2f(ou.z) + bf2f(au.z), v3 = bf2f(ou.w) + bf2f(au.w);
  float s = v0 + v1 + v2 + v3;
  float q = v0 * v0 + v1 * v1 + v2 * v2 + v3 * v3;
#pragma unroll
  for (int o = 32; o; o >>= 1) { s += __shfl_down(s, o); q += __shfl_down(q, o); }
  if (lane == 0) { redA[wave] = s; redB[wave] = q; }
  __syncthreads();
  float S = redA[0] + redA[1] + redA[2] + redA[3];
  float Q = redB[0] + redB[1] + redB[2] + redB[3];
  float mu = S * (1.f / 1024.f);
  float var = Q * (1.f / 1024.f) - mu * mu;
  float rs = rsqrtf(var + 1e-5f);
  float4 gg = ((const float4*)g)[t], bbv = ((const float4*)b)[t];
  ushort4 ob;
  ob.x = f2bf((v0 - mu) * rs * gg.x + bbv.x);
  ob.y = f2bf((v1 - mu) * rs * gg.y + bbv.y);
  ob.z = f2bf((v2 - mu) * rs * gg.z + bbv.z);
  ob.w = f2bf((v3 - mu) * rs * gg.w + bbv.w);
  ((ushort4*)(xb + row * 1024))[t] = ob;
}

// ---------------- LN2: y = LN(y0)*g + b, f32 in-place safe ----------------
__global__ __launch_bounds__(256) void ln2_k(const float* __restrict__ Y,
                                             const float* __restrict__ g, const float* __restrict__ b,
                                             float* __restrict__ out, float eps) {
  __shared__ float redA[4], redB[4];
  const long long row = blockIdx.x;
  const int t = threadIdx.x, wave = t >> 6, lane = t & 63;
  float4 v = ((const float4*)(Y + row * 1024))[t];
  float s = v.x + v.y + v.z + v.w;
  float q = v.x * v.x + v.y * v.y + v.z * v.z + v.w * v.w;
#pragma unroll
  for (int o = 32; o; o >>= 1) { s += __shfl_down(s, o); q += __shfl_down(q, o); }
  if (lane == 0) { redA[wave] = s; redB[wave] = q; }
  __syncthreads();
  float S = redA[0] + redA[1] + redA[2] + redA[3];
  float Q = redB[0] + redB[1] + redB[2] + redB[3];
  float mu = S * (1.f / 1024.f);
  float var = Q * (1.f / 1024.f) - mu * mu;
  float rs = rsqrtf(var + eps);
  float4 gg = ((const float4*)g)[t], bbv = ((const float4*)b)[t];
  float4 o;
  o.x = (v.x - mu) * rs * gg.x + bbv.x;
  o.y = (v.y - mu) * rs * gg.y + bbv.y;
  o.z = (v.z - mu) * rs * gg.z + bbv.z;
  o.w = (v.w - mu) * rs * gg.w + bbv.w;
  ((float4*)(out + row * 1024))[t] = o;
}

// ---------------- launcher ----------------
extern "C" void kernel_launch(void* const* d_in, const int* in_sizes, int n_in,
                              void* d_out, int out_size, void* d_ws, size_t ws_size,
                              hipStream_t stream) {
  (void)in_sizes; (void)n_in; (void)out_size;
  if (ws_size < (size_t)WS_NEED) return; // diagnostic guard (absmax ~7.09 if hit)

  static int attr_once = []() {
    (void)hipFuncSetAttribute(reinterpret_cast<const void*>(&gemm256<1>),
                              hipFuncAttributeMaxDynamicSharedMemorySize, 65536);
    (void)hipFuncSetAttribute(reinterpret_cast<const void*>(&gemm256<2>),
                              hipFuncAttributeMaxDynamicSharedMemorySize, 65536);
    (void)hipFuncSetAttribute(reinterpret_cast<const void*>(&gemm256<3>),
                              hipFuncAttributeMaxDynamicSharedMemorySize, 65536);
    return 0;
  }();
  (void)attr_once;

  const float* Fs  = (const float*)d_in[0];
  const float* Fq  = (const float*)d_in[1];
  const float* Fms = (const float*)d_in[2];
  const float* Wm[6] = {(const float*)d_in[4], (const float*)d_in[5], (const float*)d_in[6],
                        (const float*)d_in[7], (const float*)d_in[8], (const float*)d_in[9]};
  const float* Wq = (const float*)d_in[10];
  const float* Wk = (const float*)d_in[11];
  const float* Wv = (const float*)d_in[12];
  const float* ln_g = (const float*)d_in[13];
  const float* ln_b = (const float*)d_in[14];
  const float* fw1 = (const float*)d_in[15];
  const float* fw2 = (const float*)d_in[16];
  const float* fg = (const float*)d_in[17];
  const float* fb = (const float*)d_in[18];
  float* out = (float*)d_out;
  uint8_t* ws = (uint8_t*)d_ws;
  auto U16 = [&](long long off) { return (unsigned short*)(ws + off); };

  const float inv_sqrt512 = 0.04419417382415922f; // 1/sqrt(512) == 1/sqrt(g)
  dim3 blk(256);

  auto gemm = [&](int ep, const unsigned short* A, long long sA, long long hA, int lda,
                  const unsigned short* B, long long sB, long long hB, int ldb,
                  void* C, long long sC, long long hC, int ldc, const void* R, long long sR,
                  int M, int N, int K, int batch) {
    dim3 g(M / 256, N / 256, batch);
    dim3 b(512);
    switch (ep) {
      case 1: gemm256<1><<<g, b, 65536, stream>>>(A, sA, hA, lda, B, sB, hB, ldb, C, sC, hC, ldc, R, sR, K); break;
      case 2: gemm256<2><<<g, b, 65536, stream>>>(A, sA, hA, lda, B, sB, hB, ldb, C, sC, hC, ldc, R, sR, K); break;
      default: gemm256<3><<<g, b, 65536, stream>>>(A, sA, hA, lda, B, sB, hB, ldb, C, sC, hC, ldc, R, sR, K); break;
    }
  };

  // ---- weights: transpose+cast to bf16 (merged dispatches) ----
  tcast6_k<<<dim3(16, 16, 6), dim3(32, 8), 0, stream>>>(
      Wm[0], Wm[1], Wm[2], Wm[3], Wm[4], Wm[5], U16(O_WT), 512, 512);
  tcast6_k<<<dim3(32, 32, 5), dim3(32, 8), 0, stream>>>(
      Wq, Wk, Wv, fw1, fw2, fw2 /*unused*/, U16(O_WQT), 1024, 1024);
  // ---- input casts (before any affinity output is written) ----
  cast3_k<<<dim3(E1e / 4 / 256, 3), blk, 0, stream>>>(
      Fs, Fq, Fms, U16(O_FSB), U16(O_FQB), U16(O_FMSB));

  // ---- Phase A: affinities ----
  // merged: z=0: Cp = Fms @ [W1|W2] -> S0 ; z=1: Cq45 = Fq @ [W4|W5] -> S1
  gemm(1, U16(O_FMSB), 16777216, 0, 512, U16(O_WT), 786432, 0, 512,
       U16(O_S0), 16777216, 0, 1024, nullptr, 0, (int)BN, 1024, 512, 2);
  // ass raw scores = P0 P1^T -> E0
  gemm(1, U16(O_S0), Nn * 1024, 0, 1024, U16(O_S0) + 512, Nn * 1024, 0, 1024,
       U16(O_E0), Nn * Nn, 0, 1024, nullptr, 0, 1024, 1024, 512, (int)Bb);
  // merged: z=0: C2 = Fs@W3 -> C2 ; z=1: Cq6 = Fq@W6 -> S2
  gemm(1, U16(O_FSB), 8388608, 0, 512, U16(O_WT + 2 * SZ_W512), 786432, 0, 512,
       U16(O_C2), -58720256LL, 0, 512, nullptr, 0, (int)BN, 512, 512, 2);
  // asq raw scores = C2 Cq45[:, :512]^T -> E1 (overwrites FsB, dead)
  gemm(1, U16(O_C2), Nn * 512, 0, 512, U16(O_S1), Nn * 1024, 0, 1024,
       U16(O_E1), Nn * Nn, 0, 1024, nullptr, 0, 1024, 1024, 512, (int)Bb);
  // aqq raw scores = Cq45[:, 512:] Cq6^T -> E2 (overwrites FqB+C2, dead)
  gemm(1, U16(O_S1) + 512, Nn * 1024, 0, 1024, U16(O_S2), Nn * 512, 0, 512,
       U16(O_E2), Nn * Nn, 0, 1024, nullptr, 0, 1024, 1024, 512, (int)Bb);
  // one softmax over E0|E1|E2 (contiguous slots)
  softmax_bf<<<dim3(3 * BN), blk, 0, stream>>>(U16(O_E0), inv_sqrt512);

  const unsigned short* assB = U16(O_E0);

  // ---- Phase B ----
  // merged K+Q: z2=0 -> K = ass@Wk -> S1 ; z2=1 -> Q = asq@Wq -> S0
  gemm(1, assB, Nn * Nn, E2n, 1024,
       U16(O_WKT), 0, -(long long)(SZ_W1K / 2), 1024,
       U16(O_S1), Nn * 1024, -(long long)E2n, 1024,
       nullptr, 0, 1024, 1024, 1024, 32);
  // Vt[b][c][q] -> S2 (operand-swapped NT)
  gemm(1, U16(O_WVT), 0, 0, 1024, U16(O_E1), Nn * Nn, 0, 1024, U16(O_S2), Nn * Nn, 0, 1024,
       nullptr, 0, 1024, 1024, 1024, (int)Bb);

  // attention scores, both heads in one batch-32 dispatch -> E0(z2=0), E1(z2=1)
  gemm(1, U16(O_S0), Nn * 1024, 512, 1024, U16(O_S1), Nn * 1024, 512, 1024,
       U16(O_E0), Nn * Nn, 16 * Nn * Nn, 1024, nullptr, 0, 1024, 1024, 512, 32);
  softmax_bf<<<dim3(2 * BN), blk, 0, stream>>>(U16(O_E0), inv_sqrt512);

  // o = attn @ V, both heads, batch 32 -> S0 (Q dead)
  gemm(1, U16(O_E0), Nn * Nn, 16 * Nn * Nn, 1024, U16(O_S2), Nn * Nn, 512 * 1024, 1024,
       U16(O_S0), Nn * 1024, 512, 1024, nullptr, 0, 1024, 512, 1024, 32);

  // x = LN(o + aqq) -> bf16 -> S1 (K dead)
  ln1_k<<<dim3(BN), blk, 0, stream>>>(U16(O_S0), U16(O_E2), ln_g, ln_b, U16(O_S1));

  // h = relu(x @ ffn_w1) -> S2 (Vt dead)
  gemm(2, U16(O_S1), 0, 0, 1024, U16(O_F1T), 0, 0, 1024, U16(O_S2), 0, 0, 1024,
       nullptr, 0, (int)BN, 1024, 1024, 1);

  // y0 = h @ ffn_w2 + x -> f32 into d_out
  gemm(3, U16(O_S2), 0, 0, 1024, U16(O_F2T), 0, 0, 1024, out, 0, 0, 1024,
       U16(O_S1), 0, (int)BN, 1024, 1024, 1);

  // y = LN(y0) in place on d_out
  ln2_k<<<dim3(BN), blk, 0, stream>>>(out, fg, fb, out, 1e-6f);
}

// Round 6
// 702.505 us; speedup vs baseline: 1.2313x; 1.2313x over previous
//
#include <hip/hip_runtime.h>
#include <cstdint>

// ---------------- problem constants ----------------
static constexpr long long Bb = 16, Nn = 1024, FE = 512; // heads=2, g=512
static constexpr long long BN = Bb * Nn;        // 16384
static constexpr long long E1e = BN * FE;       // elems of [B,N,FE] (8388608)
static constexpr long long E2n = BN * Nn;       // elems of [B,N,N]

// ---------------- workspace layout (bytes) ----------------
static constexpr long long O_WT  = 0;                      // 6x 512x512 bf16 (plain cast W1..W6)
static constexpr long long SZ_W512 = FE * FE * 2;
static constexpr long long O_WQT = O_WT + 6 * SZ_W512;     // 1024-transposed weights
static constexpr long long SZ_W1K = Nn * Nn * 2;
static constexpr long long O_WKT = O_WQT + SZ_W1K;
static constexpr long long O_WVT = O_WKT + SZ_W1K;
static constexpr long long O_F1T = O_WVT + SZ_W1K;
static constexpr long long O_F2T = O_F1T + SZ_W1K;
static constexpr long long O_SLOTS = O_F2T + SZ_W1K;       // 13,631,488
static constexpr long long SLOT = E2n * 2;                 // 32 MiB
static constexpr long long O_S0 = O_SLOTS;                 // P planes -> Q -> o
static constexpr long long O_S1 = O_S0 + SLOT;             // P tail -> K -> x
static constexpr long long O_S2 = O_S1 + SLOT;             // Gt -> aqq -> h
static constexpr long long O_E0 = O_S2 + SLOT;             // F planes -> asq -> scores h1
static constexpr long long O_E1 = O_E0 + SLOT;             // Fq plane -> Vt
static constexpr long long O_E2 = O_E1 + SLOT;             // ass -> scores h0
static constexpr long long WS_NEED = O_E2 + SLOT;          // ~205 MiB
// phase-A temporaries:
static constexpr long long O_FB = O_E0;                    // F planes [Fms|Fs|Fq], stride E1e elems
static constexpr long long O_GT = O_S2;                    // 3x 512x512 Gt planes (dead after P)

// ---------------- helpers ----------------
typedef __attribute__((ext_vector_type(8))) short short8;
typedef __attribute__((ext_vector_type(4))) float f32x4;

static __device__ __forceinline__ unsigned short f2bf(float f) {
  union { float f; unsigned u; } x; x.f = f;
  unsigned r = x.u + 0x7FFFu + ((x.u >> 16) & 1u);
  return (unsigned short)(r >> 16);
}
static __device__ __forceinline__ float bf2f(unsigned short h) {
  union { unsigned u; float f; } x; x.u = ((unsigned)h) << 16; return x.f;
}
static __device__ __forceinline__ void gload16(const void* g, void* l) {
  __builtin_amdgcn_global_load_lds(
      (const __attribute__((address_space(1))) unsigned int*)g,
      (__attribute__((address_space(3))) unsigned int*)l, 16, 0, 0);
}

// ---------------- bf16 NT GEMM, 256x256 tile, ring-4, 2-phase K-step ---------
// (Round-4 verified core: 718us total, MfmaUtil 36.5, 0 bank conflicts.)
// C[m,n] = sum_k A[m,k]*B[n,k].  8 waves (2M x 4N), per-wave output 128x64.
// BK=32 per K-step; 4 LDS buffers of 32 KiB, tile t -> buf t&3.
//   phase A: read bfr0-3,af0-3(t); stage A-halves(t+3); bar; 16 MFMA m0-3; bar
//   phase B: read af4-7(t);        stage B-halves(t+3); vmcnt(8); bar;
//            16 MFMA m4-7; bar
// vmcnt(8): 12 outstanding -> retires tile t+1's 4 loads.
// LDS swizzle: slot s of row r holds k-slot s ^ ((r>>1)&3); linear gload_lds
// dest + pre-swizzled global source + swizzled ds_read.
// XCD swizzle: bijective m204 variant (handles nwg % 8 != 0).
// Batch z decodes z1=z&15, z2=z>>4: operand offset = z1*s? + z2*h?.
// EP: 1 = bf16 out, 2 = bf16 relu out, 3 = f32 out + bf16 residual R.
template <int EP>
__global__ __launch_bounds__(512, 2) void gemm256(
    const unsigned short* __restrict__ A, long long sA, long long hA, int lda,
    const unsigned short* __restrict__ B, long long sB, long long hB, int ldb,
    void* __restrict__ Cv, long long sC, long long hC, int ldc,
    const void* __restrict__ Rv, long long sR, int K) {
  extern __shared__ unsigned short lds[];
  const int tid = threadIdx.x;
  const int lane = tid & 63;
  const int wave = tid >> 6;
  const int wm = wave >> 2, wn = wave & 3;
  const int lrow = lane & 15, quad = lane >> 4;

  // bijective XCD swizzle (m204): works for any nwg
  const int gx = gridDim.x;
  const int nxy = gx * gridDim.y;
  const int nwg = nxy * gridDim.z;
  int wg = blockIdx.x + gx * blockIdx.y + nxy * blockIdx.z;
  {
    const int q = nwg >> 3, r = nwg & 7;
    const int xcd = wg & 7, blk = wg >> 3;
    wg = (xcd < r ? xcd * (q + 1) : r * (q + 1) + (xcd - r) * q) + blk;
  }
  const int bz = wg / nxy;
  const int rem = wg - bz * nxy;
  const int by = rem / gx;
  const int bx = rem - by * gx;
  const int z1 = bz & 15, z2 = bz >> 4;

  const long long bm = (long long)bx * 256;
  const long long bn = (long long)by * 256;
  const unsigned short* Ab = A + z1 * sA + z2 * hA + bm * lda;
  const unsigned short* Bp = B + z1 * sB + z2 * hB + bn * ldb;

  // staging: thread covers row (tid>>2) (+128 for 2nd round), 16B slot (tid&3).
  const int srow = tid >> 2;
  const int scol = ((tid & 3) ^ ((tid >> 3) & 3)) * 8;  // elems
  unsigned short* ldst = lds + tid * 8;

  // read side: lane (lrow,quad) reads swizzled slot quad ^ ((lrow>>1)&3).
  const int swq = (quad ^ ((lrow >> 1) & 3)) * 8;
  const int a_off = (wm * 128 + lrow) * 32 + swq;
  const int b_off = 8192 + (wn * 64 + lrow) * 32 + swq;

  f32x4 acc[8][4];
#pragma unroll
  for (int m = 0; m < 8; ++m)
#pragma unroll
    for (int n = 0; n < 4; ++n) acc[m][n] = (f32x4){0.f, 0.f, 0.f, 0.f};

  short8 af[8], bfr[4];
  auto READ_A0 = [&](int tt) {   // bfr0-3 + af0-3  (8 ds_read_b128)
    const unsigned short* lb = lds + (tt & 3) * 16384;
    bfr[0] = *(const short8*)&lb[b_off + 0 * 512];
    bfr[1] = *(const short8*)&lb[b_off + 1 * 512];
    bfr[2] = *(const short8*)&lb[b_off + 2 * 512];
    bfr[3] = *(const short8*)&lb[b_off + 3 * 512];
#pragma unroll
    for (int m = 0; m < 4; ++m) af[m] = *(const short8*)&lb[a_off + m * 512];
  };
  auto READ_A1 = [&](int tt) {   // af4-7  (4 ds_read_b128)
    const unsigned short* lb = lds + (tt & 3) * 16384;
#pragma unroll
    for (int m = 4; m < 8; ++m) af[m] = *(const short8*)&lb[a_off + m * 512];
  };
  auto MFMA_H = [&](int m0) {    // 16 MFMA: m = m0..m0+3
    __builtin_amdgcn_s_setprio(1);
#pragma unroll
    for (int m = m0; m < m0 + 4; ++m)
#pragma unroll
      for (int n = 0; n < 4; ++n)
        acc[m][n] = __builtin_amdgcn_mfma_f32_16x16x32_bf16(af[m], bfr[n], acc[m][n], 0, 0, 0);
    __builtin_amdgcn_s_setprio(0);
  };
  auto STAGE = [&](int tt) {     // full tile (prologue only)
    unsigned short* d = ldst + (tt & 3) * 16384;
    const long long ko = (long long)tt * 32 + scol;
    gload16(Ab + (long long)srow * lda + ko, d);
    gload16(Ab + (long long)(srow + 128) * lda + ko, d + 4096);
    gload16(Bp + (long long)srow * ldb + ko, d + 8192);
    gload16(Bp + (long long)(srow + 128) * ldb + ko, d + 12288);
  };

  const int nt = K >> 5;   // >= 16 here
  STAGE(0); STAGE(1); STAGE(2);
  asm volatile("s_waitcnt vmcnt(8)" ::: "memory");   // STAGE(0) retired
  __builtin_amdgcn_s_barrier();                      // buf0 globally ready
  int t = 0;
  for (; t < nt - 3; ++t) {
    unsigned short* d = ldst + ((t + 3) & 3) * 16384;
    const long long ko = (long long)(t + 3) * 32 + scol;
    // ---- phase A ----
    READ_A0(t);
    gload16(Ab + (long long)srow * lda + ko, d);
    gload16(Ab + (long long)(srow + 128) * lda + ko, d + 4096);
    __builtin_amdgcn_s_barrier();
    MFMA_H(0);
    __builtin_amdgcn_s_barrier();
    // ---- phase B ----
    READ_A1(t);
    gload16(Bp + (long long)srow * ldb + ko, d + 8192);
    gload16(Bp + (long long)(srow + 128) * ldb + ko, d + 12288);
    asm volatile("s_waitcnt vmcnt(8)" ::: "memory"); // tile t+1's loads retired
    __builtin_amdgcn_s_barrier();                    // buf[t+1] globally ready
    MFMA_H(4);
    __builtin_amdgcn_s_barrier();                    // reads done before overwrite
  }
  // ---- tail: t = nt-3 (drain 8 -> 4) ----
  READ_A0(t);
  __builtin_amdgcn_s_barrier();
  MFMA_H(0);
  __builtin_amdgcn_s_barrier();
  READ_A1(t);
  asm volatile("s_waitcnt vmcnt(4)" ::: "memory");
  __builtin_amdgcn_s_barrier();
  MFMA_H(4);
  __builtin_amdgcn_s_barrier();
  ++t;
  // ---- tail: t = nt-2 (drain 4 -> 0) ----
  READ_A0(t);
  __builtin_amdgcn_s_barrier();
  MFMA_H(0);
  __builtin_amdgcn_s_barrier();
  READ_A1(t);
  asm volatile("s_waitcnt vmcnt(0)" ::: "memory");
  __builtin_amdgcn_s_barrier();
  MFMA_H(4);
  __builtin_amdgcn_s_barrier();
  ++t;
  // ---- tail: t = nt-1 ----
  READ_A0(t);
  MFMA_H(0);
  READ_A1(t);
  MFMA_H(4);

  // epilogue: C/D map col=lane&15, row=quad*4+r (verified m89/m91)
  const long long cm = bm + wm * 128, cn = bn + wn * 64;
  const long long cz = z1 * sC + z2 * hC;
#pragma unroll
  for (int mt = 0; mt < 8; ++mt) {
#pragma unroll
    for (int ntl = 0; ntl < 4; ++ntl) {
      long long col = cn + ntl * 16 + lrow;
      long long row0 = cm + mt * 16 + quad * 4;
#pragma unroll
      for (int r = 0; r < 4; ++r) {
        long long row = row0 + r;
        float v = acc[mt][ntl][r];
        long long idx = cz + row * ldc + col;
        if (EP == 1) ((unsigned short*)Cv)[idx] = f2bf(v);
        else if (EP == 2) ((unsigned short*)Cv)[idx] = f2bf(v > 0.f ? v : 0.f);
        else {
          float rr = bf2f(((const unsigned short*)Rv)[z1 * sR + row * ldc + col]);
          ((float*)Cv)[idx] = v + rr;
        }
      }
    }
  }
}

// ---------------- merged cast f32 -> bf16, 3 planes per dispatch ----------------
__global__ __launch_bounds__(256) void cast3_k(const float* __restrict__ i0,
                                               const float* __restrict__ i1,
                                               const float* __restrict__ i2,
                                               unsigned short* o0, unsigned short* o1,
                                               unsigned short* o2) {
  const float* in = (blockIdx.y == 0) ? i0 : (blockIdx.y == 1) ? i1 : i2;
  unsigned short* out = (blockIdx.y == 0) ? o0 : (blockIdx.y == 1) ? o1 : o2;
  long long i = (long long)blockIdx.x * 256 + threadIdx.x;
  float4 v = ((const float4*)in)[i];
  ushort4 o; o.x = f2bf(v.x); o.y = f2bf(v.y); o.z = f2bf(v.z); o.w = f2bf(v.w);
  ((ushort4*)out)[i] = o;
}

// ---------------- merged transpose+cast: z selects source ----------------
__global__ __launch_bounds__(256) void tcast6_k(const float* p0, const float* p1,
                                                const float* p2, const float* p3,
                                                const float* p4, const float* p5,
                                                unsigned short* outb, int rows, int cols) {
  const float* src[6] = {p0, p1, p2, p3, p4, p5};
  const float* in = src[blockIdx.z];
  unsigned short* out = outb + (long long)blockIdx.z * rows * cols;
  __shared__ float t[32][33];
  const int c0 = blockIdx.x * 32, r0 = blockIdx.y * 32;
  const int tx = threadIdx.x, ty = threadIdx.y; // block (32,8)
#pragma unroll
  for (int i = 0; i < 4; ++i) {
    int r = r0 + ty + i * 8;
    t[ty + i * 8][tx] = in[(long long)r * cols + c0 + tx];
  }
  __syncthreads();
#pragma unroll
  for (int i = 0; i < 4; ++i) {
    int c = c0 + ty + i * 8;
    out[(long long)c * rows + r0 + tx] = f2bf(t[tx][ty + i * 8]);
  }
}

// ---------------- in-place row softmax over bf16 (1024 cols), scaled ----------------
__global__ __launch_bounds__(256) void softmax_bf(unsigned short* __restrict__ S, float scale) {
  __shared__ float redA[4], redB[4];
  const long long row = blockIdx.x;
  const int t = threadIdx.x, wave = t >> 6, lane = t & 63;
  ushort4 u = ((ushort4*)(S + row * 1024))[t];
  float v0 = bf2f(u.x) * scale, v1 = bf2f(u.y) * scale, v2 = bf2f(u.z) * scale, v3 = bf2f(u.w) * scale;
  float m = fmaxf(fmaxf(v0, v1), fmaxf(v2, v3));
#pragma unroll
  for (int o = 32; o; o >>= 1) m = fmaxf(m, __shfl_down(m, o));
  if (lane == 0) redA[wave] = m;
  __syncthreads();
  m = fmaxf(fmaxf(redA[0], redA[1]), fmaxf(redA[2], redA[3]));
  float e0 = __expf(v0 - m), e1 = __expf(v1 - m), e2 = __expf(v2 - m), e3 = __expf(v3 - m);
  float s = e0 + e1 + e2 + e3;
#pragma unroll
  for (int o = 32; o; o >>= 1) s += __shfl_down(s, o);
  if (lane == 0) redB[wave] = s;
  __syncthreads();
  s = redB[0] + redB[1] + redB[2] + redB[3];
  float inv = 1.f / s;
  ushort4 ob; ob.x = f2bf(e0 * inv); ob.y = f2bf(e1 * inv); ob.z = f2bf(e2 * inv); ob.w = f2bf(e3 * inv);
  ((ushort4*)(S + row * 1024))[t] = ob;
}

// ---------------- LN1: x = LN(o + aqq)*g + b -> bf16 ----------------
__global__ __launch_bounds__(256) void ln1_k(const unsigned short* __restrict__ O,
                                             const unsigned short* __restrict__ Aq,
                                             const float* __restrict__ g, const float* __restrict__ b,
                                             unsigned short* __restrict__ xb) {
  __shared__ float redA[4], redB[4];
  const long long row = blockIdx.x;
  const int t = threadIdx.x, wave = t >> 6, lane = t & 63;
  ushort4 ou = ((const ushort4*)(O + row * 1024))[t];
  ushort4 au = ((const ushort4*)(Aq + row * 1024))[t];
  float v0 = bf2f(ou.x) + bf2f(au.x), v1 = bf2f(ou.y) + bf2f(au.y);
  float v2 = bf2f(ou.z) + bf2f(au.z), v3 = bf2f(ou.w) + bf2f(au.w);
  float s = v0 + v1 + v2 + v3;
  float q = v0 * v0 + v1 * v1 + v2 * v2 + v3 * v3;
#pragma unroll
  for (int o = 32; o; o >>= 1) { s += __shfl_down(s, o); q += __shfl_down(q, o); }
  if (lane == 0) { redA[wave] = s; redB[wave] = q; }
  __syncthreads();
  float S = redA[0] + redA[1] + redA[2] + redA[3];
  float Q = redB[0] + redB[1] + redB[2] + redB[3];
  float mu = S * (1.f / 1024.f);
  float var = Q * (1.f / 1024.f) - mu * mu;
  float rs = rsqrtf(var + 1e-5f);
  float4 gg = ((const float4*)g)[t], bbv = ((const float4*)b)[t];
  ushort4 ob;
  ob.x = f2bf((v0 - mu) * rs * gg.x + bbv.x);
  ob.y = f2bf((v1 - mu) * rs * gg.y + bbv.y);
  ob.z = f2bf((v2 - mu) * rs * gg.z + bbv.z);
  ob.w = f2bf((v3 - mu) * rs * gg.w + bbv.w);
  ((ushort4*)(xb + row * 1024))[t] = ob;
}

// ---------------- LN2: y = LN(y0)*g + b, f32 in-place safe ----------------
__global__ __launch_bounds__(256) void ln2_k(const float* __restrict__ Y,
                                             const float* __restrict__ g, const float* __restrict__ b,
                                             float* __restrict__ out, float eps) {
  __shared__ float redA[4], redB[4];
  const long long row = blockIdx.x;
  const int t = threadIdx.x, wave = t >> 6, lane = t & 63;
  float4 v = ((const float4*)(Y + row * 1024))[t];
  float s = v.x + v.y + v.z + v.w;
  float q = v.x * v.x + v.y * v.y + v.z * v.z + v.w * v.w;
#pragma unroll
  for (int o = 32; o; o >>= 1) { s += __shfl_down(s, o); q += __shfl_down(q, o); }
  if (lane == 0) { redA[wave] = s; redB[wave] = q; }
  __syncthreads();
  float S = redA[0] + redA[1] + redA[2] + redA[3];
  float Q = redB[0] + redB[1] + redB[2] + redB[3];
  float mu = S * (1.f / 1024.f);
  float var = Q * (1.f / 1024.f) - mu * mu;
  float rs = rsqrtf(var + eps);
  float4 gg = ((const float4*)g)[t], bbv = ((const float4*)b)[t];
  float4 o;
  o.x = (v.x - mu) * rs * gg.x + bbv.x;
  o.y = (v.y - mu) * rs * gg.y + bbv.y;
  o.z = (v.z - mu) * rs * gg.z + bbv.z;
  o.w = (v.w - mu) * rs * gg.w + bbv.w;
  ((float4*)(out + row * 1024))[t] = o;
}

// ---------------- launcher ----------------
extern "C" void kernel_launch(void* const* d_in, const int* in_sizes, int n_in,
                              void* d_out, int out_size, void* d_ws, size_t ws_size,
                              hipStream_t stream) {
  (void)in_sizes; (void)n_in; (void)out_size;
  if (ws_size < (size_t)WS_NEED) return; // diagnostic guard (absmax ~7.09 if hit)

  static int attr_once = []() {
    (void)hipFuncSetAttribute(reinterpret_cast<const void*>(&gemm256<1>),
                              hipFuncAttributeMaxDynamicSharedMemorySize, 131072);
    (void)hipFuncSetAttribute(reinterpret_cast<const void*>(&gemm256<2>),
                              hipFuncAttributeMaxDynamicSharedMemorySize, 131072);
    (void)hipFuncSetAttribute(reinterpret_cast<const void*>(&gemm256<3>),
                              hipFuncAttributeMaxDynamicSharedMemorySize, 131072);
    return 0;
  }();
  (void)attr_once;

  const float* Fs  = (const float*)d_in[0];
  const float* Fq  = (const float*)d_in[1];
  const float* Fms = (const float*)d_in[2];
  const float* Wm[6] = {(const float*)d_in[4], (const float*)d_in[5], (const float*)d_in[6],
                        (const float*)d_in[7], (const float*)d_in[8], (const float*)d_in[9]};
  const float* Wq = (const float*)d_in[10];
  const float* Wk = (const float*)d_in[11];
  const float* Wv = (const float*)d_in[12];
  const float* ln_g = (const float*)d_in[13];
  const float* ln_b = (const float*)d_in[14];
  const float* fw1 = (const float*)d_in[15];
  const float* fw2 = (const float*)d_in[16];
  const float* fg = (const float*)d_in[17];
  const float* fb = (const float*)d_in[18];
  float* out = (float*)d_out;
  uint8_t* ws = (uint8_t*)d_ws;
  auto U16 = [&](long long off) { return (unsigned short*)(ws + off); };

  const float inv_sqrt512 = 0.04419417382415922f; // 1/sqrt(512) == 1/sqrt(g)
  dim3 blk(256);

  auto gemm = [&](int ep, const unsigned short* A, long long sA, long long hA, int lda,
                  const unsigned short* B, long long sB, long long hB, int ldb,
                  void* C, long long sC, long long hC, int ldc, const void* R, long long sR,
                  int M, int N, int K, int batch) {
    dim3 g(M / 256, N / 256, batch);
    dim3 b(512);
    switch (ep) {
      case 1: gemm256<1><<<g, b, 131072, stream>>>(A, sA, hA, lda, B, sB, hB, ldb, C, sC, hC, ldc, R, sR, K); break;
      case 2: gemm256<2><<<g, b, 131072, stream>>>(A, sA, hA, lda, B, sB, hB, ldb, C, sC, hC, ldc, R, sR, K); break;
      default: gemm256<3><<<g, b, 131072, stream>>>(A, sA, hA, lda, B, sB, hB, ldb, C, sC, hC, ldc, R, sR, K); break;
    }
  };

  // ---- weight prep ----
  // plain cast W1..W6 -> bf16 planes at O_WT (262144 elems each)
  unsigned short* Wc = U16(O_WT);
  cast3_k<<<dim3(256, 3), blk, 0, stream>>>(Wm[0], Wm[1], Wm[2], Wc, Wc + 262144, Wc + 2 * 262144);
  cast3_k<<<dim3(256, 3), blk, 0, stream>>>(Wm[3], Wm[4], Wm[5], Wc + 3 * 262144, Wc + 4 * 262144, Wc + 5 * 262144);
  // transpose+cast 1024 weights (Wq,Wk,Wv,ffn_w1,ffn_w2)
  tcast6_k<<<dim3(32, 32, 5), dim3(32, 8), 0, stream>>>(
      Wq, Wk, Wv, fw1, fw2, fw2 /*unused*/, U16(O_WQT), 1024, 1024);
  // input casts -> F planes [Fms|Fs|Fq] at O_FB (stride E1e elems)
  unsigned short* FB = U16(O_FB);
  cast3_k<<<dim3(E1e / 4 / 256, 3), blk, 0, stream>>>(
      Fms, Fs, Fq, FB, FB + E1e, FB + 2 * E1e);

  // ---- Phase A: affinities via fused weight products ----
  // Gt planes [ss,sq,qq] at O_GT: Gt_xy = NT(W_even, W_odd)  (Gt = (Wa Wb^T)^T)
  gemm(1, Wc + 262144, 524288, 0, 512, Wc, 524288, 0, 512,
       U16(O_GT), 262144, 0, 512, nullptr, 0, 512, 512, 512, 3);
  // P planes = NT(F, Gt) -> S0 (stride E1e): P_ss=Fms@G_ss, P_sq=Fs@G_sq, P_qq=Fq@G_qq
  gemm(1, FB, E1e, 0, 512, U16(O_GT), 262144, 0, 512,
       U16(O_S0), E1e, 0, 512, nullptr, 0, (int)BN, 512, 512, 3);
  // scores_ss = NT(P_ss, Fms) batch16 -> E2
  gemm(1, U16(O_S0), Nn * 512, 0, 512, FB, Nn * 512, 0, 512,
       U16(O_E2), Nn * Nn, 0, 1024, nullptr, 0, 1024, 1024, 512, (int)Bb);
  // scores_sq/qq = NT(P_sq|P_qq, Fq) batch32: z2=0 -> sq@E0, z2=1 -> qq@S2
  gemm(1, U16(O_S0) + E1e, Nn * 512, E1e, 512, FB + 2 * E1e, Nn * 512, 0, 512,
       U16(O_E0), Nn * Nn, -(long long)E2n, 1024, nullptr, 0, 1024, 1024, 512, 32);
  // softmax: qq@S2 + sq@E0 contiguous (2BN rows), ss@E2 (BN rows)
  softmax_bf<<<dim3(2 * BN), blk, 0, stream>>>(U16(O_S2), inv_sqrt512);
  softmax_bf<<<dim3(BN), blk, 0, stream>>>(U16(O_E2), inv_sqrt512);
  // bindings: ass@E2, asq@E0, aqq@S2

  // ---- Phase B ----
  // merged K+Q batch32: z2=0 -> K = ass@Wk -> S1 ; z2=1 -> Q = asq@Wq -> S0
  gemm(1, U16(O_E2), Nn * Nn, -(long long)(2 * E2n), 1024,
       U16(O_WKT), 0, -(long long)(SZ_W1K / 2), 1024,
       U16(O_S1), Nn * 1024, -(long long)E2n, 1024,
       nullptr, 0, 1024, 1024, 1024, 32);
  // Vt[b][c][q] -> E1 (operand-swapped NT; asq@E0 dead after this + scores below)
  gemm(1, U16(O_WVT), 0, 0, 1024, U16(O_E0), Nn * Nn, 0, 1024, U16(O_E1), Nn * Nn, 0, 1024,
       nullptr, 0, 1024, 1024, 1024, (int)Bb);

  // attention scores batch32: z2=0 -> h0@E2 (ass dead), z2=1 -> h1@E0 (asq dead)
  gemm(1, U16(O_S0), Nn * 1024, 512, 1024, U16(O_S1), Nn * 1024, 512, 1024,
       U16(O_E2), Nn * Nn, -(long long)(2 * E2n), 1024, nullptr, 0, 1024, 1024, 512, 32);
  softmax_bf<<<dim3(BN), blk, 0, stream>>>(U16(O_E2), inv_sqrt512);
  softmax_bf<<<dim3(BN), blk, 0, stream>>>(U16(O_E0), inv_sqrt512);

  // o = attn @ V batch32 -> S0 (Q dead)
  gemm(1, U16(O_E2), Nn * Nn, -(long long)(2 * E2n), 1024,
       U16(O_E1), Nn * Nn, (long long)(512 * 1024), 1024,
       U16(O_S0), Nn * 1024, 512, 1024, nullptr, 0, 1024, 512, 1024, 32);

  // x = LN(o + aqq) -> bf16 -> S1 (K dead)
  ln1_k<<<dim3(BN), blk, 0, stream>>>(U16(O_S0), U16(O_S2), ln_g, ln_b, U16(O_S1));

  // h = relu(x @ ffn_w1) -> S2 (aqq dead)
  gemm(2, U16(O_S1), 0, 0, 1024, U16(O_F1T), 0, 0, 1024, U16(O_S2), 0, 0, 1024,
       nullptr, 0, (int)BN, 1024, 1024, 1);

  // y0 = h @ ffn_w2 + x -> f32 into d_out
  gemm(3, U16(O_S2), 0, 0, 1024, U16(O_F2T), 0, 0, 1024, out, 0, 0, 1024,
       U16(O_S1), 0, (int)BN, 1024, 1024, 1);

  // y = LN(y0) in place on d_out
  ln2_k<<<dim3(BN), blk, 0, stream>>>(out, fg, fb, out, 1e-6f);
}